// Round 13
// baseline (137.854 us; speedup 1.0000x reference)
//
#include <hip/hip_runtime.h>
#include <hip/hip_bf16.h>
#include <math.h>

#define N_NODES 50000
#define N_EDGES 800000
#define E_TOT   (N_EDGES + N_NODES)
#define IN_DIM  128
#define HID     128      // HEADS*HIDDEN (layer-1 output width)
#define ODIM    64
#define NEG     0.2f
#define NB1     ((N_NODES + 255) / 256)   // scan blocks = 196
#define NCHUNK  ((N_NODES + 31) / 32)     // 32-node chunks for MFMA GEMMs
#define NREP    16
#define MM1B    512                        // mm1 blocks in the fused mm1+hist dispatch
#define EGRID   ((E_TOT + 255) / 256)      // hist/scatter blocks = 3321

typedef short bf16x8 __attribute__((ext_vector_type(8)));
typedef float f32x4 __attribute__((ext_vector_type(4)));
typedef float f32x2 __attribute__((ext_vector_type(2)));
typedef unsigned short ushort_t;

__device__ __forceinline__ float lrelu(float x) { return x >= 0.f ? x : NEG * x; }

// bf16 <-> f32 helpers (RNE rounding on store)
__device__ __forceinline__ unsigned short f2b(float v) {
  unsigned int b = __float_as_uint(v);
  b += 0x7fffu + ((b >> 16) & 1u);
  return (unsigned short)(b >> 16);
}
__device__ __forceinline__ unsigned int f2b2(float lo, float hi) {
  union { __hip_bfloat162 h; unsigned int u; } cv;
  cv.h = __float22bfloat162_rn(make_float2(lo, hi));
  return cv.u;
}
// fp8 e4m3 (OCP) hardware converts
__device__ __forceinline__ f32x2 f8x2lo(unsigned int v) {
  return __builtin_amdgcn_cvt_pk_f32_fp8((int)v, false);
}
__device__ __forceinline__ f32x2 f8x2hi(unsigned int v) {
  return __builtin_amdgcn_cvt_pk_f32_fp8((int)v, true);
}
__device__ __forceinline__ unsigned char f2f8(float v) {
  return (unsigned char)(__builtin_amdgcn_cvt_pk_fp8_f32(v, v, 0, false) & 0xff);
}

__device__ __forceinline__ int e_src(const void* ei, int f, int e) {
  if (e >= N_EDGES) return e - N_EDGES;              // self loop
  return f ? (int)((const long long*)ei)[e] : ((const int*)ei)[e];
}
__device__ __forceinline__ int e_dst(const void* ei, int f, int e) {
  if (e >= N_EDGES) return e - N_EDGES;              // self loop
  return f ? (int)((const long long*)ei)[N_EDGES + e] : ((const int*)ei)[N_EDGES + e];
}

// ---------- weight prep (bf16 W^T) + dtype detect + degr/ctr zero (fused memset) ----------
__global__ void k_prep(const float* __restrict__ W1, const float* __restrict__ W2,
                       ushort_t* __restrict__ Wt1, ushort_t* __restrict__ Wt2,
                       const void* ei, int* flag, int4* __restrict__ degr4,
                       int* __restrict__ ctr) {
  if (blockIdx.x == 64) {
    if (threadIdx.x == 0) {
      const int* p = (const int*)ei;
      int allz = 1;
      for (int i = 0; i < 64; ++i) if (p[2 * i + 1] != 0) { allz = 0; break; }
      *flag = allz;  // 1 => buffer is int64
    }
    if (threadIdx.x == 1) *ctr = 0;
    return;
  }
  if (blockIdx.x > 64) {   // zero degr: NREP*N_NODES ints = 200000 int4
    int i = (blockIdx.x - 65) * 256 + threadIdx.x;
    if (i < NREP * N_NODES / 4) degr4[i] = make_int4(0, 0, 0, 0);
    return;
  }
  int i = blockIdx.x * 256 + threadIdx.x;
  if (i < 128 * 128) { int k = i >> 7, n = i & 127; Wt1[n * 128 + k] = f2b(W1[i]); }
  if (i < 128 * 64)  { int k = i >> 6, n = i & 63;  Wt2[n * 128 + k] = f2b(W2[i]); }
}

// ---------- fused scan: block-local scan + publish + spin + finalize (one dispatch) ----------
__global__ __launch_bounds__(256) void k_scan(const int* __restrict__ degr, int* __restrict__ offs,
                                              int* __restrict__ repbase, int* __restrict__ bsums,
                                              int* __restrict__ ctr) {
  __shared__ int sm[256];
  __shared__ int red[4];
  int t = threadIdx.x, b = blockIdx.x;
  int i = b * 256 + t;
  int v = 0;
  if (i < N_NODES) {
    #pragma unroll
    for (int r = 0; r < NREP; ++r) v += degr[r * N_NODES + i];
  }
  sm[t] = v;
  __syncthreads();
  for (int o = 1; o < 256; o <<= 1) {
    int add = (t >= o) ? sm[t - o] : 0;
    __syncthreads();
    sm[t] += add;
    __syncthreads();
  }
  int lexcl = sm[t] - v;   // block-local exclusive prefix
  if (t == 255) {
    __hip_atomic_store(&bsums[b], sm[255], __ATOMIC_RELEASE, __HIP_MEMORY_SCOPE_AGENT);
    __threadfence();
    atomicAdd(ctr, 1);
  }
  if (t == 0) {
    while (__hip_atomic_load(ctr, __ATOMIC_ACQUIRE, __HIP_MEMORY_SCOPE_AGENT) < (int)gridDim.x) {}
  }
  __syncthreads();
  int p = (t < b) ? __hip_atomic_load(&bsums[t], __ATOMIC_ACQUIRE, __HIP_MEMORY_SCOPE_AGENT) : 0;
  #pragma unroll
  for (int o = 32; o >= 1; o >>= 1) p += __shfl_xor(p, o);
  if ((t & 63) == 0) red[t >> 6] = p;
  __syncthreads();
  int pre = red[0] + red[1] + red[2] + red[3];
  if (i < N_NODES) {
    int o = lexcl + pre;
    offs[i] = o;
    int run = o;
    #pragma unroll
    for (int r = 0; r < NREP; ++r) {
      repbase[r * N_NODES + i] = run;
      run += degr[r * N_NODES + i];
    }
  }
  if (i == 0) offs[N_NODES] = E_TOT;
}

__global__ void k_scatter(const void* ei, const int* __restrict__ flag,
                          const int* __restrict__ repbase, const int* __restrict__ rank,
                          const int* __restrict__ dst32, int* __restrict__ srcs) {
  int e = blockIdx.x * 256 + threadIdx.x;
  if (e >= E_TOT) return;
  int d = dst32[e];
  int r = blockIdx.x & (NREP - 1);
  srcs[repbase[r * N_NODES + d] + rank[e]] = e_src(ei, *flag, e);
}

// ---------- FUSED: MFMA GEMM1 (blocks < MM1B) + histogram (blocks >= MM1B) ----------
// GEMM1: h1f8(fp8) = fp8(bf16(x) @ W1); als1/ald1 computed in epilogue (no h1b buffer).
__global__ __launch_bounds__(256) void k_mm1h(const float* __restrict__ x,
                                              const ushort_t* __restrict__ Wt,
                                              unsigned char* __restrict__ h1f8,
                                              float* __restrict__ als1,
                                              float* __restrict__ ald1,
                                              const float* __restrict__ asrc,
                                              const float* __restrict__ adst,
                                              const void* ei, const int* __restrict__ flag,
                                              int* __restrict__ degr, int* __restrict__ rank,
                                              int* __restrict__ dst32) {
  if (blockIdx.x >= MM1B) {     // ---- histogram path ----
    int e = (blockIdx.x - MM1B) * 256 + threadIdx.x;
    if (e < E_TOT) {
      int r = (blockIdx.x - MM1B) & (NREP - 1);
      int d = e_dst(ei, *flag, e);
      rank[e] = atomicAdd(&degr[r * N_NODES + d], 1);
      dst32[e] = d;
    }
    return;
  }
  // ---- GEMM1 path ----
  __shared__ ushort_t xs[32 * 128];   // 8 KB
  int t = threadIdx.x;
  int w = t >> 6, l = t & 63;
  int lr = l & 15, lk = l >> 4;
  int nodeSub = (w & 1) * 16, colBase = (w >> 1) * 64;
  int headBase = colBase >> 5;        // 0 or 2
  bf16x8 bfrag[4][4];
  #pragma unroll
  for (int ct = 0; ct < 4; ++ct)
    #pragma unroll
    for (int ks = 0; ks < 4; ++ks) {
      int n = colBase + ct * 16 + lr;
      int k = ks * 32 + lk * 8;
      bfrag[ct][ks] = *(const bf16x8*)&Wt[n * 128 + k];
    }
  float as0 = asrc[colBase + lr],      as1v = asrc[colBase + 16 + lr];
  float as2 = asrc[colBase + 32 + lr], as3 = asrc[colBase + 48 + lr];
  float ad0 = adst[colBase + lr],      ad1v = adst[colBase + 16 + lr];
  float ad2 = adst[colBase + 32 + lr], ad3 = adst[colBase + 48 + lr];
  int rr = t >> 3, c0 = (t & 7) * 16;   // staging: row, 16-elem col group
  for (int chunk = blockIdx.x; chunk < NCHUNK; chunk += MM1B) {
    int base = chunk * 32;
    int srcRow = base + rr; if (srcRow >= N_NODES) srcRow = N_NODES - 1;
    const float4* xr = (const float4*)&x[(size_t)srcRow * IN_DIM + c0];
    float4 f0 = xr[0], f1 = xr[1], f2 = xr[2], f3 = xr[3];
    uint4 w0, w1;
    w0.x = f2b2(f0.x, f0.y); w0.y = f2b2(f0.z, f0.w);
    w0.z = f2b2(f1.x, f1.y); w0.w = f2b2(f1.z, f1.w);
    w1.x = f2b2(f2.x, f2.y); w1.y = f2b2(f2.z, f2.w);
    w1.z = f2b2(f3.x, f3.y); w1.w = f2b2(f3.z, f3.w);
    char* xsb = (char*)xs;
    int swz = (rr & 7) << 4;
    *(uint4*)(xsb + rr * 256 + ((c0 * 2 +  0) ^ swz)) = w0;
    *(uint4*)(xsb + rr * 256 + ((c0 * 2 + 16) ^ swz)) = w1;
    __syncthreads();
    f32x4 acc[4] = {{0,0,0,0},{0,0,0,0},{0,0,0,0},{0,0,0,0}};
    int arow = nodeSub + lr;
    #pragma unroll
    for (int ks = 0; ks < 4; ++ks) {
      bf16x8 a = *(const bf16x8*)((const char*)xs + arow * 256 +
                                  ((ks * 64 + lk * 16) ^ ((arow & 7) << 4)));
      #pragma unroll
      for (int ct = 0; ct < 4; ++ct)
        acc[ct] = __builtin_amdgcn_mfma_f32_16x16x32_bf16(a, bfrag[ct][ks], acc[ct], 0, 0, 0);
    }
    __syncthreads();
    #pragma unroll
    for (int r = 0; r < 4; ++r) {
      int node = base + nodeSub + lk * 4 + r;
      if (node < N_NODES) {
        h1f8[(size_t)node * HID + colBase +      lr] = f2f8(acc[0][r]);
        h1f8[(size_t)node * HID + colBase + 16 + lr] = f2f8(acc[1][r]);
        h1f8[(size_t)node * HID + colBase + 32 + lr] = f2f8(acc[2][r]);
        h1f8[(size_t)node * HID + colBase + 48 + lr] = f2f8(acc[3][r]);
      }
      float s01 = acc[0][r] * as0 + acc[1][r] * as1v;
      float s23 = acc[2][r] * as2 + acc[3][r] * as3;
      float d01 = acc[0][r] * ad0 + acc[1][r] * ad1v;
      float d23 = acc[2][r] * ad2 + acc[3][r] * ad3;
      #pragma unroll
      for (int o = 1; o <= 8; o <<= 1) {
        s01 += __shfl_xor(s01, o); s23 += __shfl_xor(s23, o);
        d01 += __shfl_xor(d01, o); d23 += __shfl_xor(d23, o);
      }
      if (lr == 0 && node < N_NODES) {
        als1[node * 4 + headBase]     = s01;
        als1[node * 4 + headBase + 1] = s23;
        ald1[node * 4 + headBase]     = d01;
        ald1[node * 4 + headBase + 1] = d23;
      }
    }
  }
}

// ---------- MFMA GEMM2: h2f8(fp8) = fp8(out1b @ W2); als2/ald2 fused in epilogue ----------
__global__ __launch_bounds__(256) void k_mm2(const ushort_t* __restrict__ xb,
                                             const ushort_t* __restrict__ Wt,
                                             unsigned char* __restrict__ h2f8,
                                             float* __restrict__ als2,
                                             float* __restrict__ ald2,
                                             const float* __restrict__ asrc,
                                             const float* __restrict__ adst) {
  __shared__ ushort_t xs[32 * 128];   // 8 KB
  __shared__ float als_lds[32], ald_lds[32];
  int t = threadIdx.x;
  int w = t >> 6, l = t & 63;
  int lr = l & 15, lk = l >> 4;
  int nodeSub = (w & 1) * 16, colBase = (w >> 1) * 32;
  bf16x8 bfrag[2][4];
  #pragma unroll
  for (int ct = 0; ct < 2; ++ct)
    #pragma unroll
    for (int ks = 0; ks < 4; ++ks) {
      int n = colBase + ct * 16 + lr;
      int k = ks * 32 + lk * 8;
      bfrag[ct][ks] = *(const bf16x8*)&Wt[n * 128 + k];
    }
  float as0 = asrc[colBase + lr], as1v = asrc[colBase + 16 + lr];
  float ad0 = adst[colBase + lr], ad1v = adst[colBase + 16 + lr];
  int rr = t >> 3, c0 = (t & 7) * 16;
  for (int chunk = blockIdx.x; chunk < NCHUNK; chunk += gridDim.x) {
    int base = chunk * 32;
    int srcRow = base + rr; if (srcRow >= N_NODES) srcRow = N_NODES - 1;
    const uint4* xr = (const uint4*)&xb[(size_t)srcRow * HID + c0];
    uint4 w0 = xr[0], w1 = xr[1];
    char* xsb = (char*)xs;
    int swz = (rr & 7) << 4;
    *(uint4*)(xsb + rr * 256 + ((c0 * 2 +  0) ^ swz)) = w0;
    *(uint4*)(xsb + rr * 256 + ((c0 * 2 + 16) ^ swz)) = w1;
    __syncthreads();
    f32x4 acc[2] = {{0,0,0,0},{0,0,0,0}};
    int arow = nodeSub + lr;
    #pragma unroll
    for (int ks = 0; ks < 4; ++ks) {
      bf16x8 a = *(const bf16x8*)((const char*)xs + arow * 256 +
                                  ((ks * 64 + lk * 16) ^ ((arow & 7) << 4)));
      #pragma unroll
      for (int ct = 0; ct < 2; ++ct)
        acc[ct] = __builtin_amdgcn_mfma_f32_16x16x32_bf16(a, bfrag[ct][ks], acc[ct], 0, 0, 0);
    }
    if (t < 32) { als_lds[t] = 0.f; ald_lds[t] = 0.f; }
    __syncthreads();
    #pragma unroll
    for (int r = 0; r < 4; ++r) {
      int nodeLocal = nodeSub + lk * 4 + r;
      int node = base + nodeLocal;
      if (node < N_NODES) {
        h2f8[(size_t)node * ODIM + colBase +      lr] = f2f8(acc[0][r]);
        h2f8[(size_t)node * ODIM + colBase + 16 + lr] = f2f8(acc[1][r]);
      }
      float s = acc[0][r] * as0 + acc[1][r] * as1v;
      float d = acc[0][r] * ad0 + acc[1][r] * ad1v;
      #pragma unroll
      for (int o = 1; o <= 8; o <<= 1) {
        s += __shfl_xor(s, o);
        d += __shfl_xor(d, o);
      }
      if (lr == 0) {
        atomicAdd(&als_lds[nodeLocal], s);   // two colBase waves combine here
        atomicAdd(&ald_lds[nodeLocal], d);
      }
    }
    __syncthreads();
    if (t < 32) {
      int node = base + t;
      if (node < N_NODES) { als2[node] = als_lds[t]; ald2[node] = ald_lds[t]; }
    }
  }
}

// ---------- layer-1 aggregate: TWO nodes per wave; SUBGROUP-UNIFORM loads (no bpermute) ----------
__global__ __launch_bounds__(256) void k_agg1(const unsigned char* __restrict__ h1f8,
                                              const float* __restrict__ als,
                                              const float* __restrict__ ald, const int* __restrict__ offs,
                                              const int* __restrict__ srcs, const float* __restrict__ b1,
                                              ushort_t* __restrict__ out1b) {
  int t = threadIdx.x;
  int w = t >> 6, l = t & 63;
  int hw = l >> 5, lh = l & 31;          // half index, lane-in-half
  int sg = lh >> 4, cl = lh & 15, head = cl >> 2;
  int n = blockIdx.x * 8 + w * 2 + hw;   // grid = N/8 = 6250 exact
  int off0 = offs[n], deg = offs[n + 1] - off0;
  float adh = ald[n * 4 + head];
  const unsigned char* hb = h1f8 + cl * 8;

  float ds = 0.f;
  float num0 = 0, num1 = 0, num2 = 0, num3 = 0, num4 = 0, num5 = 0, num6 = 0, num7 = 0;

  int j = sg;
  for (; j + 2 < deg; j += 4) {
    int sA = srcs[off0 + j];
    int sB = srcs[off0 + j + 2];
    float aA = als[sA * 4 + head];
    float aB = als[sB * 4 + head];
    uint2 vA = *(const uint2*)(hb + (sA << 7));
    uint2 vB = *(const uint2*)(hb + (sB << 7));
    float wA = __expf(lrelu(aA + adh));
    float wB = __expf(lrelu(aB + adh));
    ds += wA + wB;
    f32x2 p0 = f8x2lo(vA.x), p1 = f8x2hi(vA.x);
    f32x2 p2 = f8x2lo(vA.y), p3 = f8x2hi(vA.y);
    num0 = fmaf(wA, p0.x, num0); num1 = fmaf(wA, p0.y, num1);
    num2 = fmaf(wA, p1.x, num2); num3 = fmaf(wA, p1.y, num3);
    num4 = fmaf(wA, p2.x, num4); num5 = fmaf(wA, p2.y, num5);
    num6 = fmaf(wA, p3.x, num6); num7 = fmaf(wA, p3.y, num7);
    p0 = f8x2lo(vB.x); p1 = f8x2hi(vB.x);
    p2 = f8x2lo(vB.y); p3 = f8x2hi(vB.y);
    num0 = fmaf(wB, p0.x, num0); num1 = fmaf(wB, p0.y, num1);
    num2 = fmaf(wB, p1.x, num2); num3 = fmaf(wB, p1.y, num3);
    num4 = fmaf(wB, p2.x, num4); num5 = fmaf(wB, p2.y, num5);
    num6 = fmaf(wB, p3.x, num6); num7 = fmaf(wB, p3.y, num7);
  }
  if (j < deg) {
    int sA = srcs[off0 + j];
    float aA = als[sA * 4 + head];
    uint2 vA = *(const uint2*)(hb + (sA << 7));
    float wA = __expf(lrelu(aA + adh));
    ds += wA;
    f32x2 p0 = f8x2lo(vA.x), p1 = f8x2hi(vA.x);
    f32x2 p2 = f8x2lo(vA.y), p3 = f8x2hi(vA.y);
    num0 = fmaf(wA, p0.x, num0); num1 = fmaf(wA, p0.y, num1);
    num2 = fmaf(wA, p1.x, num2); num3 = fmaf(wA, p1.y, num3);
    num4 = fmaf(wA, p2.x, num4); num5 = fmaf(wA, p2.y, num5);
    num6 = fmaf(wA, p3.x, num6); num7 = fmaf(wA, p3.y, num7);
  }
  num0 += __shfl_xor(num0, 16); num1 += __shfl_xor(num1, 16);
  num2 += __shfl_xor(num2, 16); num3 += __shfl_xor(num3, 16);
  num4 += __shfl_xor(num4, 16); num5 += __shfl_xor(num5, 16);
  num6 += __shfl_xor(num6, 16); num7 += __shfl_xor(num7, 16);
  ds += __shfl_xor(ds, 16);
  if (lh < 16) {
    float rd = 1.f / ds;
    int c8 = cl * 8;
    float4 bb0 = *(const float4*)&b1[c8];
    float4 bb1 = *(const float4*)&b1[c8 + 4];
    float o0 = fmaxf(num0 * rd + bb0.x, 0.f);
    float o1 = fmaxf(num1 * rd + bb0.y, 0.f);
    float o2 = fmaxf(num2 * rd + bb0.z, 0.f);
    float o3 = fmaxf(num3 * rd + bb0.w, 0.f);
    float o4 = fmaxf(num4 * rd + bb1.x, 0.f);
    float o5 = fmaxf(num5 * rd + bb1.y, 0.f);
    float o6 = fmaxf(num6 * rd + bb1.z, 0.f);
    float o7 = fmaxf(num7 * rd + bb1.w, 0.f);
    uint4 pk;
    pk.x = f2b2(o0, o1); pk.y = f2b2(o2, o3);
    pk.z = f2b2(o4, o5); pk.w = f2b2(o6, o7);
    *(uint4*)&out1b[(size_t)n * HID + c8] = pk;
  }
}

// ---------- layer-2 aggregate + log_softmax: TWO nodes per wave; subgroup-uniform loads ----------
__global__ __launch_bounds__(256) void k_agg2(const unsigned char* __restrict__ h2f8,
                                              const float* __restrict__ als,
                                              const float* __restrict__ ald, const int* __restrict__ offs,
                                              const int* __restrict__ srcs, const float* __restrict__ b2,
                                              float* __restrict__ out) {
  int t = threadIdx.x;
  int w = t >> 6, l = t & 63;
  int hw = l >> 5, lh = l & 31;
  int sg = lh >> 3, cl = lh & 7;
  int n = blockIdx.x * 8 + w * 2 + hw;
  int off0 = offs[n], deg = offs[n + 1] - off0;
  float adv = ald[n];
  const unsigned char* hb = h2f8 + cl * 8;

  float ds = 0.f;
  float num0 = 0, num1 = 0, num2 = 0, num3 = 0, num4 = 0, num5 = 0, num6 = 0, num7 = 0;

  int j = sg;
  for (; j + 4 < deg; j += 8) {
    int sA = srcs[off0 + j];
    int sB = srcs[off0 + j + 4];
    float aA = als[sA];
    float aB = als[sB];
    uint2 vA = *(const uint2*)(hb + (sA << 6));
    uint2 vB = *(const uint2*)(hb + (sB << 6));
    float wA = __expf(lrelu(aA + adv));
    float wB = __expf(lrelu(aB + adv));
    ds += wA + wB;
    f32x2 p0 = f8x2lo(vA.x), p1 = f8x2hi(vA.x);
    f32x2 p2 = f8x2lo(vA.y), p3 = f8x2hi(vA.y);
    num0 = fmaf(wA, p0.x, num0); num1 = fmaf(wA, p0.y, num1);
    num2 = fmaf(wA, p1.x, num2); num3 = fmaf(wA, p1.y, num3);
    num4 = fmaf(wA, p2.x, num4); num5 = fmaf(wA, p2.y, num5);
    num6 = fmaf(wA, p3.x, num6); num7 = fmaf(wA, p3.y, num7);
    p0 = f8x2lo(vB.x); p1 = f8x2hi(vB.x);
    p2 = f8x2lo(vB.y); p3 = f8x2hi(vB.y);
    num0 = fmaf(wB, p0.x, num0); num1 = fmaf(wB, p0.y, num1);
    num2 = fmaf(wB, p1.x, num2); num3 = fmaf(wB, p1.y, num3);
    num4 = fmaf(wB, p2.x, num4); num5 = fmaf(wB, p2.y, num5);
    num6 = fmaf(wB, p3.x, num6); num7 = fmaf(wB, p3.y, num7);
  }
  if (j < deg) {
    int sA = srcs[off0 + j];
    float aA = als[sA];
    uint2 vA = *(const uint2*)(hb + (sA << 6));
    float wA = __expf(lrelu(aA + adv));
    ds += wA;
    f32x2 p0 = f8x2lo(vA.x), p1 = f8x2hi(vA.x);
    f32x2 p2 = f8x2lo(vA.y), p3 = f8x2hi(vA.y);
    num0 = fmaf(wA, p0.x, num0); num1 = fmaf(wA, p0.y, num1);
    num2 = fmaf(wA, p1.x, num2); num3 = fmaf(wA, p1.y, num3);
    num4 = fmaf(wA, p2.x, num4); num5 = fmaf(wA, p2.y, num5);
    num6 = fmaf(wA, p3.x, num6); num7 = fmaf(wA, p3.y, num7);
  }
  #pragma unroll
  for (int o = 8; o <= 16; o <<= 1) {
    num0 += __shfl_xor(num0, o); num1 += __shfl_xor(num1, o);
    num2 += __shfl_xor(num2, o); num3 += __shfl_xor(num3, o);
    num4 += __shfl_xor(num4, o); num5 += __shfl_xor(num5, o);
    num6 += __shfl_xor(num6, o); num7 += __shfl_xor(num7, o);
    ds += __shfl_xor(ds, o);
  }
  if (lh < 8) {
    float rd = 1.f / ds;
    int c8 = cl * 8;
    float4 bb0 = *(const float4*)&b2[c8];
    float4 bb1 = *(const float4*)&b2[c8 + 4];
    float v0 = num0 * rd + bb0.x, v1 = num1 * rd + bb0.y;
    float v2 = num2 * rd + bb0.z, v3 = num3 * rd + bb0.w;
    float v4 = num4 * rd + bb1.x, v5 = num5 * rd + bb1.y;
    float v6 = num6 * rd + bb1.z, v7 = num7 * rd + bb1.w;
    float mx = fmaxf(fmaxf(fmaxf(v0, v1), fmaxf(v2, v3)), fmaxf(fmaxf(v4, v5), fmaxf(v6, v7)));
    #pragma unroll
    for (int o = 1; o <= 4; o <<= 1) mx = fmaxf(mx, __shfl_xor(mx, o));
    float sum = __expf(v0 - mx) + __expf(v1 - mx) + __expf(v2 - mx) + __expf(v3 - mx)
              + __expf(v4 - mx) + __expf(v5 - mx) + __expf(v6 - mx) + __expf(v7 - mx);
    #pragma unroll
    for (int o = 1; o <= 4; o <<= 1) sum += __shfl_xor(sum, o);
    float ls = __logf(sum);
    float4 r0, r1;
    r0.x = (v0 - mx) - ls; r0.y = (v1 - mx) - ls; r0.z = (v2 - mx) - ls; r0.w = (v3 - mx) - ls;
    r1.x = (v4 - mx) - ls; r1.y = (v5 - mx) - ls; r1.z = (v6 - mx) - ls; r1.w = (v7 - mx) - ls;
    *(float4*)&out[(size_t)n * ODIM + c8] = r0;
    *(float4*)&out[(size_t)n * ODIM + c8 + 4] = r1;
  }
}

extern "C" void kernel_launch(void* const* d_in, const int* in_sizes, int n_in,
                              void* d_out, int out_size, void* d_ws, size_t ws_size,
                              hipStream_t stream) {
  const float* x   = (const float*)d_in[0];
  const void*  ei  = d_in[1];
  const float* W1  = (const float*)d_in[2];
  const float* as1 = (const float*)d_in[3];
  const float* ad1 = (const float*)d_in[4];
  const float* b1  = (const float*)d_in[5];
  const float* W2  = (const float*)d_in[6];
  const float* as2 = (const float*)d_in[7];
  const float* ad2 = (const float*)d_in[8];
  const float* b2  = (const float*)d_in[9];
  float* out = (float*)d_out;

  char* ws = (char*)d_ws;
  size_t o = 0;
  auto alloc = [&](size_t bytes) { void* p = (void*)(ws + o); o += (bytes + 255) & ~(size_t)255; return p; };
  ushort_t* out1b = (ushort_t*)alloc((size_t)N_NODES * HID * 2);
  unsigned char* h1f8 = (unsigned char*)alloc((size_t)N_NODES * HID);
  ushort_t* Wt1   = (ushort_t*)alloc((size_t)128 * 128 * 2);
  ushort_t* Wt2   = (ushort_t*)alloc((size_t)64 * 128 * 2);
  float* als1 = (float*)alloc((size_t)N_NODES * 4 * 4);
  float* ald1 = (float*)alloc((size_t)N_NODES * 4 * 4);
  float* als2 = (float*)alloc((size_t)N_NODES * 4);
  float* ald2 = (float*)alloc((size_t)N_NODES * 4);
  int*   degr = (int*)alloc((size_t)NREP * N_NODES * 4);
  int*   repbase = (int*)alloc((size_t)NREP * N_NODES * 4);
  int*   offs = (int*)alloc((size_t)(N_NODES + 1) * 4);
  int*   rank = (int*)alloc((size_t)E_TOT * 4);
  int*   dst32 = (int*)alloc((size_t)E_TOT * 4);
  int*   srcs = (int*)alloc((size_t)E_TOT * 4);
  int*   bsums= (int*)alloc((size_t)NB1 * 4);
  int*   flag = (int*)alloc(4);
  int*   ctr  = (int*)alloc(4);
  // h2f8 (3.2 MB) aliases rank (3.4 MB): rank is dead after k_scatter
  unsigned char* h2f8 = (unsigned char*)rank;

  // k_prep: blocks 0..63 weight prep, 64 detect+ctr-zero, 65.. zero degr (fused memset)
  int prepGrid = 65 + (NREP * N_NODES / 4 + 255) / 256;
  k_prep   <<<prepGrid, 256, 0, stream>>>(W1, W2, Wt1, Wt2, ei, flag, (int4*)degr, ctr);

  // fused GEMM1 + histogram (data-independent, run concurrently)
  k_mm1h   <<<MM1B + EGRID, 256, 0, stream>>>(x, Wt1, h1f8, als1, ald1, as1, ad1,
                                              ei, flag, degr, rank, dst32);
  k_scan   <<<NB1, 256, 0, stream>>>(degr, offs, repbase, bsums, ctr);
  k_scatter<<<EGRID, 256, 0, stream>>>(ei, flag, repbase, rank, dst32, srcs);

  k_agg1 <<<N_NODES / 8, 256, 0, stream>>>(h1f8, als1, ald1, offs, srcs, b1, out1b);

  k_mm2  <<<512, 256, 0, stream>>>(out1b, Wt2, h2f8, als2, ald2, as2, ad2);
  k_agg2 <<<N_NODES / 8, 256, 0, stream>>>(h2f8, als2, ald2, offs, srcs, b2, out);
}

// Round 14
// 120.044 us; speedup vs baseline: 1.1484x; 1.1484x over previous
//
#include <hip/hip_runtime.h>
#include <hip/hip_bf16.h>
#include <math.h>

#define N_NODES 50000
#define N_EDGES 800000
#define E_TOT   (N_EDGES + N_NODES)
#define IN_DIM  128
#define HID     128      // HEADS*HIDDEN (layer-1 output width)
#define ODIM    64
#define NEG     0.2f
#define NB1     ((N_NODES + 255) / 256)   // scan blocks = 196
#define NCHUNK  ((N_NODES + 31) / 32)     // 32-node chunks for MFMA GEMMs
#define NREP    8
#define MM1B    512                        // mm1 blocks in the fused mm1+hist dispatch
#define EGRID   ((E_TOT + 255) / 256)      // hist/scatter blocks = 3321

typedef short bf16x8 __attribute__((ext_vector_type(8)));
typedef float f32x4 __attribute__((ext_vector_type(4)));
typedef float f32x2 __attribute__((ext_vector_type(2)));
typedef unsigned short ushort_t;

__device__ __forceinline__ float lrelu(float x) { return x >= 0.f ? x : NEG * x; }

// bf16 <-> f32 helpers (RNE rounding on store)
__device__ __forceinline__ unsigned short f2b(float v) {
  unsigned int b = __float_as_uint(v);
  b += 0x7fffu + ((b >> 16) & 1u);
  return (unsigned short)(b >> 16);
}
__device__ __forceinline__ unsigned int f2b2(float lo, float hi) {
  union { __hip_bfloat162 h; unsigned int u; } cv;
  cv.h = __float22bfloat162_rn(make_float2(lo, hi));
  return cv.u;
}
// fp8 e4m3 (OCP) hardware converts
__device__ __forceinline__ f32x2 f8x2lo(unsigned int v) {
  return __builtin_amdgcn_cvt_pk_f32_fp8((int)v, false);
}
__device__ __forceinline__ f32x2 f8x2hi(unsigned int v) {
  return __builtin_amdgcn_cvt_pk_f32_fp8((int)v, true);
}
__device__ __forceinline__ unsigned char f2f8(float v) {
  return (unsigned char)(__builtin_amdgcn_cvt_pk_fp8_f32(v, v, 0, false) & 0xff);
}

__device__ __forceinline__ int e_src(const void* ei, int f, int e) {
  if (e >= N_EDGES) return e - N_EDGES;              // self loop
  return f ? (int)((const long long*)ei)[e] : ((const int*)ei)[e];
}
__device__ __forceinline__ int e_dst(const void* ei, int f, int e) {
  if (e >= N_EDGES) return e - N_EDGES;              // self loop
  return f ? (int)((const long long*)ei)[N_EDGES + e] : ((const int*)ei)[N_EDGES + e];
}

// ---------- weight prep (bf16 W^T) + dtype detect + degr zero (fused memset) ----------
__global__ void k_prep(const float* __restrict__ W1, const float* __restrict__ W2,
                       ushort_t* __restrict__ Wt1, ushort_t* __restrict__ Wt2,
                       const void* ei, int* flag, int4* __restrict__ degr4) {
  if (blockIdx.x == 64) {
    if (threadIdx.x == 0) {
      const int* p = (const int*)ei;
      int allz = 1;
      for (int i = 0; i < 64; ++i) if (p[2 * i + 1] != 0) { allz = 0; break; }
      *flag = allz;  // 1 => buffer is int64
    }
    return;
  }
  if (blockIdx.x > 64) {   // zero degr: NREP*N_NODES ints = 100000 int4
    int i = (blockIdx.x - 65) * 256 + threadIdx.x;
    if (i < NREP * N_NODES / 4) degr4[i] = make_int4(0, 0, 0, 0);
    return;
  }
  int i = blockIdx.x * 256 + threadIdx.x;
  if (i < 128 * 128) { int k = i >> 7, n = i & 127; Wt1[n * 128 + k] = f2b(W1[i]); }
  if (i < 128 * 64)  { int k = i >> 6, n = i & 63;  Wt2[n * 128 + k] = f2b(W2[i]); }
}

__global__ void k_scan1(const int* __restrict__ degr, int* __restrict__ offs, int* __restrict__ bsums) {
  __shared__ int sm[256];
  int t = threadIdx.x, i = blockIdx.x * 256 + t;
  int v = 0;
  if (i < N_NODES) {
    #pragma unroll
    for (int r = 0; r < NREP; ++r) v += degr[r * N_NODES + i];
  }
  sm[t] = v;
  __syncthreads();
  for (int o = 1; o < 256; o <<= 1) {
    int add = (t >= o) ? sm[t - o] : 0;
    __syncthreads();
    sm[t] += add;
    __syncthreads();
  }
  if (i < N_NODES) offs[i] = sm[t] - v;   // exclusive (block-local)
  if (t == 255) bsums[blockIdx.x] = sm[255];
}

// finalize offs (recomputes bsums prefix in-block; no separate scan2) + per-replica bases
__global__ void k_scan3(int* __restrict__ offs, const int* __restrict__ bsums,
                        const int* __restrict__ degr, int* __restrict__ repbase) {
  __shared__ int red[4];
  int t = threadIdx.x;
  int v = (t < blockIdx.x) ? bsums[t] : 0;          // NB1 = 196 <= 256 threads
  #pragma unroll
  for (int o = 32; o >= 1; o >>= 1) v += __shfl_xor(v, o);
  if ((t & 63) == 0) red[t >> 6] = v;
  __syncthreads();
  int pre = red[0] + red[1] + red[2] + red[3];
  int i = blockIdx.x * 256 + t;
  if (i < N_NODES) {
    int o = offs[i] + pre;
    offs[i] = o;
    int run = o;
    #pragma unroll
    for (int r = 0; r < NREP; ++r) {
      repbase[r * N_NODES + i] = run;
      run += degr[r * N_NODES + i];
    }
  }
  if (i == 0) offs[N_NODES] = E_TOT;
}

__global__ void k_scatter(const void* ei, const int* __restrict__ flag,
                          const int* __restrict__ repbase,
                          const int* __restrict__ rank, int* __restrict__ srcs) {
  int e = blockIdx.x * 256 + threadIdx.x;
  if (e >= E_TOT) return;
  int f = *flag;
  int d = e_dst(ei, f, e);
  int r = blockIdx.x & (NREP - 1);
  srcs[repbase[r * N_NODES + d] + rank[e]] = e_src(ei, f, e);
}

// ---------- FUSED: MFMA GEMM1 (blocks < MM1B) + histogram (blocks >= MM1B) ----------
// GEMM1: h1f8(fp8) = fp8(bf16(x) @ W1); als1/ald1 computed in epilogue (no h1b buffer).
__global__ __launch_bounds__(256) void k_mm1h(const float* __restrict__ x,
                                              const ushort_t* __restrict__ Wt,
                                              unsigned char* __restrict__ h1f8,
                                              float* __restrict__ als1,
                                              float* __restrict__ ald1,
                                              const float* __restrict__ asrc,
                                              const float* __restrict__ adst,
                                              const void* ei, const int* __restrict__ flag,
                                              int* __restrict__ degr, int* __restrict__ rank) {
  if (blockIdx.x >= MM1B) {     // ---- histogram path ----
    int e = (blockIdx.x - MM1B) * 256 + threadIdx.x;
    if (e < E_TOT) {
      int r = (blockIdx.x - MM1B) & (NREP - 1);
      int d = e_dst(ei, *flag, e);
      rank[e] = atomicAdd(&degr[r * N_NODES + d], 1);
    }
    return;
  }
  // ---- GEMM1 path ----
  __shared__ ushort_t xs[32 * 128];   // 8 KB
  int t = threadIdx.x;
  int w = t >> 6, l = t & 63;
  int lr = l & 15, lk = l >> 4;
  int nodeSub = (w & 1) * 16, colBase = (w >> 1) * 64;
  int headBase = colBase >> 5;        // 0 or 2
  bf16x8 bfrag[4][4];
  #pragma unroll
  for (int ct = 0; ct < 4; ++ct)
    #pragma unroll
    for (int ks = 0; ks < 4; ++ks) {
      int n = colBase + ct * 16 + lr;
      int k = ks * 32 + lk * 8;
      bfrag[ct][ks] = *(const bf16x8*)&Wt[n * 128 + k];
    }
  float as0 = asrc[colBase + lr],      as1v = asrc[colBase + 16 + lr];
  float as2 = asrc[colBase + 32 + lr], as3 = asrc[colBase + 48 + lr];
  float ad0 = adst[colBase + lr],      ad1v = adst[colBase + 16 + lr];
  float ad2 = adst[colBase + 32 + lr], ad3 = adst[colBase + 48 + lr];
  int rr = t >> 3, c0 = (t & 7) * 16;   // staging: row, 16-elem col group
  for (int chunk = blockIdx.x; chunk < NCHUNK; chunk += MM1B) {
    int base = chunk * 32;
    int srcRow = base + rr; if (srcRow >= N_NODES) srcRow = N_NODES - 1;
    const float4* xr = (const float4*)&x[(size_t)srcRow * IN_DIM + c0];
    float4 f0 = xr[0], f1 = xr[1], f2 = xr[2], f3 = xr[3];
    uint4 w0, w1;
    w0.x = f2b2(f0.x, f0.y); w0.y = f2b2(f0.z, f0.w);
    w0.z = f2b2(f1.x, f1.y); w0.w = f2b2(f1.z, f1.w);
    w1.x = f2b2(f2.x, f2.y); w1.y = f2b2(f2.z, f2.w);
    w1.z = f2b2(f3.x, f3.y); w1.w = f2b2(f3.z, f3.w);
    char* xsb = (char*)xs;
    int swz = (rr & 7) << 4;
    *(uint4*)(xsb + rr * 256 + ((c0 * 2 +  0) ^ swz)) = w0;
    *(uint4*)(xsb + rr * 256 + ((c0 * 2 + 16) ^ swz)) = w1;
    __syncthreads();
    f32x4 acc[4] = {{0,0,0,0},{0,0,0,0},{0,0,0,0},{0,0,0,0}};
    int arow = nodeSub + lr;
    #pragma unroll
    for (int ks = 0; ks < 4; ++ks) {
      bf16x8 a = *(const bf16x8*)((const char*)xs + arow * 256 +
                                  ((ks * 64 + lk * 16) ^ ((arow & 7) << 4)));
      #pragma unroll
      for (int ct = 0; ct < 4; ++ct)
        acc[ct] = __builtin_amdgcn_mfma_f32_16x16x32_bf16(a, bfrag[ct][ks], acc[ct], 0, 0, 0);
    }
    __syncthreads();
    #pragma unroll
    for (int r = 0; r < 4; ++r) {
      int node = base + nodeSub + lk * 4 + r;
      if (node < N_NODES) {
        h1f8[(size_t)node * HID + colBase +      lr] = f2f8(acc[0][r]);
        h1f8[(size_t)node * HID + colBase + 16 + lr] = f2f8(acc[1][r]);
        h1f8[(size_t)node * HID + colBase + 32 + lr] = f2f8(acc[2][r]);
        h1f8[(size_t)node * HID + colBase + 48 + lr] = f2f8(acc[3][r]);
      }
      float s01 = acc[0][r] * as0 + acc[1][r] * as1v;
      float s23 = acc[2][r] * as2 + acc[3][r] * as3;
      float d01 = acc[0][r] * ad0 + acc[1][r] * ad1v;
      float d23 = acc[2][r] * ad2 + acc[3][r] * ad3;
      #pragma unroll
      for (int o = 1; o <= 8; o <<= 1) {
        s01 += __shfl_xor(s01, o); s23 += __shfl_xor(s23, o);
        d01 += __shfl_xor(d01, o); d23 += __shfl_xor(d23, o);
      }
      if (lr == 0 && node < N_NODES) {
        als1[node * 4 + headBase]     = s01;
        als1[node * 4 + headBase + 1] = s23;
        ald1[node * 4 + headBase]     = d01;
        ald1[node * 4 + headBase + 1] = d23;
      }
    }
  }
}

// ---------- MFMA GEMM2: h2f8(fp8) = fp8(out1b @ W2); als2/ald2 fused in epilogue ----------
__global__ __launch_bounds__(256) void k_mm2(const ushort_t* __restrict__ xb,
                                             const ushort_t* __restrict__ Wt,
                                             unsigned char* __restrict__ h2f8,
                                             float* __restrict__ als2,
                                             float* __restrict__ ald2,
                                             const float* __restrict__ asrc,
                                             const float* __restrict__ adst) {
  __shared__ ushort_t xs[32 * 128];   // 8 KB
  __shared__ float als_lds[32], ald_lds[32];
  int t = threadIdx.x;
  int w = t >> 6, l = t & 63;
  int lr = l & 15, lk = l >> 4;
  int nodeSub = (w & 1) * 16, colBase = (w >> 1) * 32;
  bf16x8 bfrag[2][4];
  #pragma unroll
  for (int ct = 0; ct < 2; ++ct)
    #pragma unroll
    for (int ks = 0; ks < 4; ++ks) {
      int n = colBase + ct * 16 + lr;
      int k = ks * 32 + lk * 8;
      bfrag[ct][ks] = *(const bf16x8*)&Wt[n * 128 + k];
    }
  float as0 = asrc[colBase + lr], as1v = asrc[colBase + 16 + lr];
  float ad0 = adst[colBase + lr], ad1v = adst[colBase + 16 + lr];
  int rr = t >> 3, c0 = (t & 7) * 16;
  for (int chunk = blockIdx.x; chunk < NCHUNK; chunk += gridDim.x) {
    int base = chunk * 32;
    int srcRow = base + rr; if (srcRow >= N_NODES) srcRow = N_NODES - 1;
    const uint4* xr = (const uint4*)&xb[(size_t)srcRow * HID + c0];
    uint4 w0 = xr[0], w1 = xr[1];
    char* xsb = (char*)xs;
    int swz = (rr & 7) << 4;
    *(uint4*)(xsb + rr * 256 + ((c0 * 2 +  0) ^ swz)) = w0;
    *(uint4*)(xsb + rr * 256 + ((c0 * 2 + 16) ^ swz)) = w1;
    __syncthreads();
    f32x4 acc[2] = {{0,0,0,0},{0,0,0,0}};
    int arow = nodeSub + lr;
    #pragma unroll
    for (int ks = 0; ks < 4; ++ks) {
      bf16x8 a = *(const bf16x8*)((const char*)xs + arow * 256 +
                                  ((ks * 64 + lk * 16) ^ ((arow & 7) << 4)));
      #pragma unroll
      for (int ct = 0; ct < 2; ++ct)
        acc[ct] = __builtin_amdgcn_mfma_f32_16x16x32_bf16(a, bfrag[ct][ks], acc[ct], 0, 0, 0);
    }
    if (t < 32) { als_lds[t] = 0.f; ald_lds[t] = 0.f; }
    __syncthreads();
    #pragma unroll
    for (int r = 0; r < 4; ++r) {
      int nodeLocal = nodeSub + lk * 4 + r;
      int node = base + nodeLocal;
      if (node < N_NODES) {
        h2f8[(size_t)node * ODIM + colBase +      lr] = f2f8(acc[0][r]);
        h2f8[(size_t)node * ODIM + colBase + 16 + lr] = f2f8(acc[1][r]);
      }
      float s = acc[0][r] * as0 + acc[1][r] * as1v;
      float d = acc[0][r] * ad0 + acc[1][r] * ad1v;
      #pragma unroll
      for (int o = 1; o <= 8; o <<= 1) {
        s += __shfl_xor(s, o);
        d += __shfl_xor(d, o);
      }
      if (lr == 0) {
        atomicAdd(&als_lds[nodeLocal], s);   // two colBase waves combine here
        atomicAdd(&ald_lds[nodeLocal], d);
      }
    }
    __syncthreads();
    if (t < 32) {
      int node = base + t;
      if (node < N_NODES) { als2[node] = als_lds[t]; ald2[node] = ald_lds[t]; }
    }
  }
}

// ---------- layer-1 aggregate: TWO nodes per wave; SUBGROUP-UNIFORM loads (no bpermute) ----------
__global__ __launch_bounds__(256) void k_agg1(const unsigned char* __restrict__ h1f8,
                                              const float* __restrict__ als,
                                              const float* __restrict__ ald, const int* __restrict__ offs,
                                              const int* __restrict__ srcs, const float* __restrict__ b1,
                                              ushort_t* __restrict__ out1b) {
  int t = threadIdx.x;
  int w = t >> 6, l = t & 63;
  int hw = l >> 5, lh = l & 31;          // half index, lane-in-half
  int sg = lh >> 4, cl = lh & 15, head = cl >> 2;
  int n = blockIdx.x * 8 + w * 2 + hw;   // grid = N/8 = 6250 exact
  int off0 = offs[n], deg = offs[n + 1] - off0;
  float adh = ald[n * 4 + head];
  const unsigned char* hb = h1f8 + cl * 8;

  float ds = 0.f;
  float num0 = 0, num1 = 0, num2 = 0, num3 = 0, num4 = 0, num5 = 0, num6 = 0, num7 = 0;

  int j = sg;
  for (; j + 2 < deg; j += 4) {
    int sA = srcs[off0 + j];
    int sB = srcs[off0 + j + 2];
    float aA = als[sA * 4 + head];
    float aB = als[sB * 4 + head];
    uint2 vA = *(const uint2*)(hb + (sA << 7));
    uint2 vB = *(const uint2*)(hb + (sB << 7));
    float wA = __expf(lrelu(aA + adh));
    float wB = __expf(lrelu(aB + adh));
    ds += wA + wB;
    f32x2 p0 = f8x2lo(vA.x), p1 = f8x2hi(vA.x);
    f32x2 p2 = f8x2lo(vA.y), p3 = f8x2hi(vA.y);
    num0 = fmaf(wA, p0.x, num0); num1 = fmaf(wA, p0.y, num1);
    num2 = fmaf(wA, p1.x, num2); num3 = fmaf(wA, p1.y, num3);
    num4 = fmaf(wA, p2.x, num4); num5 = fmaf(wA, p2.y, num5);
    num6 = fmaf(wA, p3.x, num6); num7 = fmaf(wA, p3.y, num7);
    p0 = f8x2lo(vB.x); p1 = f8x2hi(vB.x);
    p2 = f8x2lo(vB.y); p3 = f8x2hi(vB.y);
    num0 = fmaf(wB, p0.x, num0); num1 = fmaf(wB, p0.y, num1);
    num2 = fmaf(wB, p1.x, num2); num3 = fmaf(wB, p1.y, num3);
    num4 = fmaf(wB, p2.x, num4); num5 = fmaf(wB, p2.y, num5);
    num6 = fmaf(wB, p3.x, num6); num7 = fmaf(wB, p3.y, num7);
  }
  if (j < deg) {
    int sA = srcs[off0 + j];
    float aA = als[sA * 4 + head];
    uint2 vA = *(const uint2*)(hb + (sA << 7));
    float wA = __expf(lrelu(aA + adh));
    ds += wA;
    f32x2 p0 = f8x2lo(vA.x), p1 = f8x2hi(vA.x);
    f32x2 p2 = f8x2lo(vA.y), p3 = f8x2hi(vA.y);
    num0 = fmaf(wA, p0.x, num0); num1 = fmaf(wA, p0.y, num1);
    num2 = fmaf(wA, p1.x, num2); num3 = fmaf(wA, p1.y, num3);
    num4 = fmaf(wA, p2.x, num4); num5 = fmaf(wA, p2.y, num5);
    num6 = fmaf(wA, p3.x, num6); num7 = fmaf(wA, p3.y, num7);
  }
  num0 += __shfl_xor(num0, 16); num1 += __shfl_xor(num1, 16);
  num2 += __shfl_xor(num2, 16); num3 += __shfl_xor(num3, 16);
  num4 += __shfl_xor(num4, 16); num5 += __shfl_xor(num5, 16);
  num6 += __shfl_xor(num6, 16); num7 += __shfl_xor(num7, 16);
  ds += __shfl_xor(ds, 16);
  if (lh < 16) {
    float rd = 1.f / ds;
    int c8 = cl * 8;
    float4 bb0 = *(const float4*)&b1[c8];
    float4 bb1 = *(const float4*)&b1[c8 + 4];
    float o0 = fmaxf(num0 * rd + bb0.x, 0.f);
    float o1 = fmaxf(num1 * rd + bb0.y, 0.f);
    float o2 = fmaxf(num2 * rd + bb0.z, 0.f);
    float o3 = fmaxf(num3 * rd + bb0.w, 0.f);
    float o4 = fmaxf(num4 * rd + bb1.x, 0.f);
    float o5 = fmaxf(num5 * rd + bb1.y, 0.f);
    float o6 = fmaxf(num6 * rd + bb1.z, 0.f);
    float o7 = fmaxf(num7 * rd + bb1.w, 0.f);
    uint4 pk;
    pk.x = f2b2(o0, o1); pk.y = f2b2(o2, o3);
    pk.z = f2b2(o4, o5); pk.w = f2b2(o6, o7);
    *(uint4*)&out1b[(size_t)n * HID + c8] = pk;
  }
}

// ---------- layer-2 aggregate + log_softmax: TWO nodes per wave; subgroup-uniform loads ----------
__global__ __launch_bounds__(256) void k_agg2(const unsigned char* __restrict__ h2f8,
                                              const float* __restrict__ als,
                                              const float* __restrict__ ald, const int* __restrict__ offs,
                                              const int* __restrict__ srcs, const float* __restrict__ b2,
                                              float* __restrict__ out) {
  int t = threadIdx.x;
  int w = t >> 6, l = t & 63;
  int hw = l >> 5, lh = l & 31;
  int sg = lh >> 3, cl = lh & 7;
  int n = blockIdx.x * 8 + w * 2 + hw;
  int off0 = offs[n], deg = offs[n + 1] - off0;
  float adv = ald[n];
  const unsigned char* hb = h2f8 + cl * 8;

  float ds = 0.f;
  float num0 = 0, num1 = 0, num2 = 0, num3 = 0, num4 = 0, num5 = 0, num6 = 0, num7 = 0;

  int j = sg;
  for (; j + 4 < deg; j += 8) {
    int sA = srcs[off0 + j];
    int sB = srcs[off0 + j + 4];
    float aA = als[sA];
    float aB = als[sB];
    uint2 vA = *(const uint2*)(hb + (sA << 6));
    uint2 vB = *(const uint2*)(hb + (sB << 6));
    float wA = __expf(lrelu(aA + adv));
    float wB = __expf(lrelu(aB + adv));
    ds += wA + wB;
    f32x2 p0 = f8x2lo(vA.x), p1 = f8x2hi(vA.x);
    f32x2 p2 = f8x2lo(vA.y), p3 = f8x2hi(vA.y);
    num0 = fmaf(wA, p0.x, num0); num1 = fmaf(wA, p0.y, num1);
    num2 = fmaf(wA, p1.x, num2); num3 = fmaf(wA, p1.y, num3);
    num4 = fmaf(wA, p2.x, num4); num5 = fmaf(wA, p2.y, num5);
    num6 = fmaf(wA, p3.x, num6); num7 = fmaf(wA, p3.y, num7);
    p0 = f8x2lo(vB.x); p1 = f8x2hi(vB.x);
    p2 = f8x2lo(vB.y); p3 = f8x2hi(vB.y);
    num0 = fmaf(wB, p0.x, num0); num1 = fmaf(wB, p0.y, num1);
    num2 = fmaf(wB, p1.x, num2); num3 = fmaf(wB, p1.y, num3);
    num4 = fmaf(wB, p2.x, num4); num5 = fmaf(wB, p2.y, num5);
    num6 = fmaf(wB, p3.x, num6); num7 = fmaf(wB, p3.y, num7);
  }
  if (j < deg) {
    int sA = srcs[off0 + j];
    float aA = als[sA];
    uint2 vA = *(const uint2*)(hb + (sA << 6));
    float wA = __expf(lrelu(aA + adv));
    ds += wA;
    f32x2 p0 = f8x2lo(vA.x), p1 = f8x2hi(vA.x);
    f32x2 p2 = f8x2lo(vA.y), p3 = f8x2hi(vA.y);
    num0 = fmaf(wA, p0.x, num0); num1 = fmaf(wA, p0.y, num1);
    num2 = fmaf(wA, p1.x, num2); num3 = fmaf(wA, p1.y, num3);
    num4 = fmaf(wA, p2.x, num4); num5 = fmaf(wA, p2.y, num5);
    num6 = fmaf(wA, p3.x, num6); num7 = fmaf(wA, p3.y, num7);
  }
  #pragma unroll
  for (int o = 8; o <= 16; o <<= 1) {
    num0 += __shfl_xor(num0, o); num1 += __shfl_xor(num1, o);
    num2 += __shfl_xor(num2, o); num3 += __shfl_xor(num3, o);
    num4 += __shfl_xor(num4, o); num5 += __shfl_xor(num5, o);
    num6 += __shfl_xor(num6, o); num7 += __shfl_xor(num7, o);
    ds += __shfl_xor(ds, o);
  }
  if (lh < 8) {
    float rd = 1.f / ds;
    int c8 = cl * 8;
    float4 bb0 = *(const float4*)&b2[c8];
    float4 bb1 = *(const float4*)&b2[c8 + 4];
    float v0 = num0 * rd + bb0.x, v1 = num1 * rd + bb0.y;
    float v2 = num2 * rd + bb0.z, v3 = num3 * rd + bb0.w;
    float v4 = num4 * rd + bb1.x, v5 = num5 * rd + bb1.y;
    float v6 = num6 * rd + bb1.z, v7 = num7 * rd + bb1.w;
    float mx = fmaxf(fmaxf(fmaxf(v0, v1), fmaxf(v2, v3)), fmaxf(fmaxf(v4, v5), fmaxf(v6, v7)));
    #pragma unroll
    for (int o = 1; o <= 4; o <<= 1) mx = fmaxf(mx, __shfl_xor(mx, o));
    float sum = __expf(v0 - mx) + __expf(v1 - mx) + __expf(v2 - mx) + __expf(v3 - mx)
              + __expf(v4 - mx) + __expf(v5 - mx) + __expf(v6 - mx) + __expf(v7 - mx);
    #pragma unroll
    for (int o = 1; o <= 4; o <<= 1) sum += __shfl_xor(sum, o);
    float ls = __logf(sum);
    float4 r0, r1;
    r0.x = (v0 - mx) - ls; r0.y = (v1 - mx) - ls; r0.z = (v2 - mx) - ls; r0.w = (v3 - mx) - ls;
    r1.x = (v4 - mx) - ls; r1.y = (v5 - mx) - ls; r1.z = (v6 - mx) - ls; r1.w = (v7 - mx) - ls;
    *(float4*)&out[(size_t)n * ODIM + c8] = r0;
    *(float4*)&out[(size_t)n * ODIM + c8 + 4] = r1;
  }
}

extern "C" void kernel_launch(void* const* d_in, const int* in_sizes, int n_in,
                              void* d_out, int out_size, void* d_ws, size_t ws_size,
                              hipStream_t stream) {
  const float* x   = (const float*)d_in[0];
  const void*  ei  = d_in[1];
  const float* W1  = (const float*)d_in[2];
  const float* as1 = (const float*)d_in[3];
  const float* ad1 = (const float*)d_in[4];
  const float* b1  = (const float*)d_in[5];
  const float* W2  = (const float*)d_in[6];
  const float* as2 = (const float*)d_in[7];
  const float* ad2 = (const float*)d_in[8];
  const float* b2  = (const float*)d_in[9];
  float* out = (float*)d_out;

  char* ws = (char*)d_ws;
  size_t o = 0;
  auto alloc = [&](size_t bytes) { void* p = (void*)(ws + o); o += (bytes + 255) & ~(size_t)255; return p; };
  ushort_t* out1b = (ushort_t*)alloc((size_t)N_NODES * HID * 2);
  unsigned char* h1f8 = (unsigned char*)alloc((size_t)N_NODES * HID);
  ushort_t* Wt1   = (ushort_t*)alloc((size_t)128 * 128 * 2);
  ushort_t* Wt2   = (ushort_t*)alloc((size_t)64 * 128 * 2);
  float* als1 = (float*)alloc((size_t)N_NODES * 4 * 4);
  float* ald1 = (float*)alloc((size_t)N_NODES * 4 * 4);
  float* als2 = (float*)alloc((size_t)N_NODES * 4);
  float* ald2 = (float*)alloc((size_t)N_NODES * 4);
  int*   degr = (int*)alloc((size_t)NREP * N_NODES * 4);
  int*   repbase = (int*)alloc((size_t)NREP * N_NODES * 4);
  int*   offs = (int*)alloc((size_t)(N_NODES + 1) * 4);
  int*   rank = (int*)alloc((size_t)E_TOT * 4);
  int*   srcs = (int*)alloc((size_t)E_TOT * 4);
  int*   bsums= (int*)alloc((size_t)NB1 * 4);
  int*   flag = (int*)alloc(4);
  // h2f8 (3.2 MB) aliases rank (3.4 MB): rank is dead after k_scatter
  unsigned char* h2f8 = (unsigned char*)rank;

  // k_prep: blocks 0..63 weight prep, 64 detect, 65.. zero degr (fused memset)
  int prepGrid = 65 + (NREP * N_NODES / 4 + 255) / 256;
  k_prep   <<<prepGrid, 256, 0, stream>>>(W1, W2, Wt1, Wt2, ei, flag, (int4*)degr);

  // fused GEMM1 + histogram (data-independent, run concurrently)
  k_mm1h   <<<MM1B + EGRID, 256, 0, stream>>>(x, Wt1, h1f8, als1, ald1, as1, ad1,
                                              ei, flag, degr, rank);
  k_scan1  <<<NB1, 256, 0, stream>>>(degr, offs, bsums);
  k_scan3  <<<NB1, 256, 0, stream>>>(offs, bsums, degr, repbase);
  k_scatter<<<EGRID, 256, 0, stream>>>(ei, flag, repbase, rank, srcs);

  k_agg1 <<<N_NODES / 8, 256, 0, stream>>>(h1f8, als1, ald1, offs, srcs, b1, out1b);

  k_mm2  <<<512, 256, 0, stream>>>(out1b, Wt2, h2f8, als2, ald2, as2, ad2);
  k_agg2 <<<N_NODES / 8, 256, 0, stream>>>(h2f8, als2, ald2, offs, srcs, b2, out);
}